// Round 1
// baseline (108.205 us; speedup 1.0000x reference)
//
#include <hip/hip_runtime.h>

// Sparsegen (sigma=0 => sparsemax) along last dim of a [32768, 2048] f32 tensor.
// One 64-lane wave per row; 32 elements/lane held in registers (8 x float4).
// tau found by Michelot's algorithm (no sort): tau <- (sum_{z>tau} z - 1)/count,
// starting from the full set. Monotone-converging; the equality-break is
// wave-uniform because the butterfly reduction leaves the result in all lanes.

#define N_COLS 2048

__global__ __launch_bounds__(256) void sparsemax_kernel(
    const float* __restrict__ x, float* __restrict__ out, int n_rows) {
    const int lane = threadIdx.x & 63;
    const int wave = threadIdx.x >> 6;
    const int row  = blockIdx.x * 4 + wave;
    if (row >= n_rows) return;

    const float4* __restrict__ xin  =
        reinterpret_cast<const float4*>(x + (size_t)row * N_COLS);
    float4* __restrict__ xout =
        reinterpret_cast<float4*>(out + (size_t)row * N_COLS);

    // Coalesced load: lane-contiguous float4 (64 lanes x 16B = 1KB/instr).
    float4 v[8];
#pragma unroll
    for (int j = 0; j < 8; ++j) v[j] = xin[j * 64 + lane];

    // ---- row max (butterfly reduce, result in all lanes) ----
    float m = -INFINITY;
#pragma unroll
    for (int j = 0; j < 8; ++j)
        m = fmaxf(m, fmaxf(fmaxf(v[j].x, v[j].y), fmaxf(v[j].z, v[j].w)));
#pragma unroll
    for (int off = 32; off >= 1; off >>= 1)
        m = fmaxf(m, __shfl_xor(m, off, 64));

    // ---- z = x - max; total sum for the first Michelot step ----
    float s = 0.0f;
#pragma unroll
    for (int j = 0; j < 8; ++j) {
        v[j].x -= m; v[j].y -= m; v[j].z -= m; v[j].w -= m;
        s += (v[j].x + v[j].y) + (v[j].z + v[j].w);
    }
#pragma unroll
    for (int off = 32; off >= 1; off >>= 1)
        s += __shfl_xor(s, off, 64);

    float tau = (s - 1.0f) / (float)N_COLS;  // full-set estimate; tau < 0 = z_max

    // ---- Michelot iterations: support shrinks monotonically, tau increases ----
    for (int it = 0; it < 64; ++it) {
        float ps = 0.0f, pc = 0.0f;
#pragma unroll
        for (int j = 0; j < 8; ++j) {
            if (v[j].x > tau) { ps += v[j].x; pc += 1.0f; }
            if (v[j].y > tau) { ps += v[j].y; pc += 1.0f; }
            if (v[j].z > tau) { ps += v[j].z; pc += 1.0f; }
            if (v[j].w > tau) { ps += v[j].w; pc += 1.0f; }
        }
#pragma unroll
        for (int off = 32; off >= 1; off >>= 1) {
            ps += __shfl_xor(ps, off, 64);
            pc += __shfl_xor(pc, off, 64);
        }
        // pc >= 1 always: argmax (z=0) stays in the set since tau < 0.
        float newtau = (ps - 1.0f) / pc;
        if (newtau == tau) break;  // wave-uniform: ps/pc identical in all lanes
        tau = newtau;
    }

    // ---- out = max(0, z - tau), coalesced float4 stores ----
#pragma unroll
    for (int j = 0; j < 8; ++j) {
        float4 o;
        o.x = fmaxf(0.0f, v[j].x - tau);
        o.y = fmaxf(0.0f, v[j].y - tau);
        o.z = fmaxf(0.0f, v[j].z - tau);
        o.w = fmaxf(0.0f, v[j].w - tau);
        xout[j * 64 + lane] = o;
    }
}

extern "C" void kernel_launch(void* const* d_in, const int* in_sizes, int n_in,
                              void* d_out, int out_size, void* d_ws, size_t ws_size,
                              hipStream_t stream) {
    const float* x = (const float*)d_in[0];
    float* out = (float*)d_out;
    int n_rows = in_sizes[0] / N_COLS;           // 32768
    int blocks = (n_rows + 3) / 4;               // 4 rows (waves) per 256-thread block
    sparsemax_kernel<<<blocks, 256, 0, stream>>>(x, out, n_rows);
}

// Round 3
// 74.428 us; speedup vs baseline: 1.4538x; 1.4538x over previous
//
#include <hip/hip_runtime.h>

// Sparsegen (sigma=0 => sparsemax) along last dim of a [32768, 2048] f32 tensor.
// One 64-lane wave per row; 32 elements/lane in registers (8 x 4 floats).
//
// Michelot's algorithm in ORIGINAL coordinates: T = m + tau,
//   T' = (sum_{x > T} x - 1) / count{x > T}
// starting from the tight lower bound T0 = m - 1 (valid since tau* >= -1:
// max(0, z_max - tau) <= sum max(0, z - tau) = 1 with z_max = 0).
// Any T <= T* yields a candidate set that is a superset of the true support,
// and for S >= S*: tau(S) <= tau*  =>  monotone convergence from below.
// For N(0,1) rows this leaves ~10-20 candidates after the first pass and
// converges in ~3-4 iterations; the z = x - max subtraction pass + its sum
// reduction disappear entirely.

#define N_COLS 2048

// Native vector type: __builtin_nontemporal_store rejects HIP's float4 class.
typedef float floatx4 __attribute__((ext_vector_type(4)));

__global__ __launch_bounds__(256) void sparsemax_kernel(
    const float* __restrict__ x, float* __restrict__ out, int n_rows) {
    const int lane = threadIdx.x & 63;
    const int wave = threadIdx.x >> 6;
    const int row  = blockIdx.x * 4 + wave;
    if (row >= n_rows) return;

    const floatx4* __restrict__ xin =
        reinterpret_cast<const floatx4*>(x + (size_t)row * N_COLS);
    floatx4* __restrict__ xout =
        reinterpret_cast<floatx4*>(out + (size_t)row * N_COLS);

    // Coalesced load: lane-contiguous 16B (64 lanes x 16B = 1KB/instr).
    floatx4 v[8];
#pragma unroll
    for (int j = 0; j < 8; ++j) v[j] = xin[j * 64 + lane];

    // ---- row max (butterfly reduce, result in all lanes) ----
    float m = -INFINITY;
#pragma unroll
    for (int j = 0; j < 8; ++j)
        m = fmaxf(m, fmaxf(fmaxf(v[j].x, v[j].y), fmaxf(v[j].z, v[j].w)));
#pragma unroll
    for (int off = 32; off >= 1; off >>= 1)
        m = fmaxf(m, __shfl_xor(m, off, 64));

    // ---- Michelot from the tight bound T0 = m - 1 ----
    float T = m - 1.0f;
    for (int it = 0; it < 64; ++it) {
        float ps = 0.0f, pc = 0.0f;
#pragma unroll
        for (int j = 0; j < 8; ++j) {
            if (v[j].x > T) { ps += v[j].x; pc += 1.0f; }
            if (v[j].y > T) { ps += v[j].y; pc += 1.0f; }
            if (v[j].z > T) { ps += v[j].z; pc += 1.0f; }
            if (v[j].w > T) { ps += v[j].w; pc += 1.0f; }
        }
#pragma unroll
        for (int off = 32; off >= 1; off >>= 1) {
            ps += __shfl_xor(ps, off, 64);
            pc += __shfl_xor(pc, off, 64);
        }
        // pc >= 1 always: the row max satisfies m > T for all T <= T* < m.
        float newT = (ps - 1.0f) / pc;
        if (!(newT > T)) break;  // wave-uniform (reduction result in all lanes)
        T = newT;
    }

    // ---- out = max(0, x - T); non-temporal stores (output never re-read,
    //      keeps the exactly-L3-sized input resident in Infinity Cache) ----
#pragma unroll
    for (int j = 0; j < 8; ++j) {
        floatx4 o;
        o.x = fmaxf(0.0f, v[j].x - T);
        o.y = fmaxf(0.0f, v[j].y - T);
        o.z = fmaxf(0.0f, v[j].z - T);
        o.w = fmaxf(0.0f, v[j].w - T);
        __builtin_nontemporal_store(o, &xout[j * 64 + lane]);
    }
}

extern "C" void kernel_launch(void* const* d_in, const int* in_sizes, int n_in,
                              void* d_out, int out_size, void* d_ws, size_t ws_size,
                              hipStream_t stream) {
    const float* x = (const float*)d_in[0];
    float* out = (float*)d_out;
    int n_rows = in_sizes[0] / N_COLS;           // 32768
    int blocks = (n_rows + 3) / 4;               // 4 rows (waves) per 256-thread block
    sparsemax_kernel<<<blocks, 256, 0, stream>>>(x, out, n_rows);
}

// Round 4
// 73.294 us; speedup vs baseline: 1.4763x; 1.0155x over previous
//
#include <hip/hip_runtime.h>

// Sparsegen (sigma=0 => sparsemax) along last dim of a [32768, 2048] f32 tensor.
// One 64-lane wave per row; 32 elements/lane in registers (8 x 4 floats).
//
// Michelot's algorithm in ORIGINAL coordinates: T = m + tau,
//   T' = (sum_{x > T} x - 1) / count{x > T}
// from the tight lower bound T0 = m - 1 (tau* >= -1). Monotone convergence
// from below; the break is wave-uniform.
//
// VALU diet (R3): the support count is computed as
//   cnt += popcount(ballot(x > T))
// = one shared v_cmp per element + s_bcnt1_b64/s_add on the SCALAR pipe,
// replacing per-element cndmask+add AND the entire 6-stage count butterfly
// (ballot is already wave-wide). Only the sum ps still needs a butterfly.

#define N_COLS 2048

// Native vector type: __builtin_nontemporal_store rejects HIP's float4 class.
typedef float floatx4 __attribute__((ext_vector_type(4)));

__global__ __launch_bounds__(256) void sparsemax_kernel(
    const float* __restrict__ x, float* __restrict__ out, int n_rows) {
    const int lane = threadIdx.x & 63;
    const int wave = threadIdx.x >> 6;
    const int row  = blockIdx.x * 4 + wave;
    if (row >= n_rows) return;

    const floatx4* __restrict__ xin =
        reinterpret_cast<const floatx4*>(x + (size_t)row * N_COLS);
    floatx4* __restrict__ xout =
        reinterpret_cast<floatx4*>(out + (size_t)row * N_COLS);

    // Coalesced load: lane-contiguous 16B (64 lanes x 16B = 1KB/instr).
    floatx4 v[8];
#pragma unroll
    for (int j = 0; j < 8; ++j) v[j] = xin[j * 64 + lane];

    // ---- row max (butterfly reduce, result in all lanes) ----
    float m = -INFINITY;
#pragma unroll
    for (int j = 0; j < 8; ++j)
        m = fmaxf(m, fmaxf(fmaxf(v[j].x, v[j].y), fmaxf(v[j].z, v[j].w)));
#pragma unroll
    for (int off = 32; off >= 1; off >>= 1)
        m = fmaxf(m, __shfl_xor(m, off, 64));

    // ---- Michelot from the tight bound T0 = m - 1 ----
    float T = m - 1.0f;
    for (int it = 0; it < 64; ++it) {
        float ps = 0.0f;
        int cnt = 0;  // wave-uniform: accumulated from ballot popcounts (SALU)
#pragma unroll
        for (int j = 0; j < 8; ++j) {
            bool gx = v[j].x > T, gy = v[j].y > T,
                 gz = v[j].z > T, gw = v[j].w > T;
            ps += gx ? v[j].x : 0.0f;
            ps += gy ? v[j].y : 0.0f;
            ps += gz ? v[j].z : 0.0f;
            ps += gw ? v[j].w : 0.0f;
            cnt += __popcll(__ballot(gx));
            cnt += __popcll(__ballot(gy));
            cnt += __popcll(__ballot(gz));
            cnt += __popcll(__ballot(gw));
        }
#pragma unroll
        for (int off = 32; off >= 1; off >>= 1)
            ps += __shfl_xor(ps, off, 64);
        // cnt >= 1 always: the row max satisfies m > T for all T <= T* < m.
        float newT = (ps - 1.0f) / (float)cnt;
        if (!(newT > T)) break;  // wave-uniform
        T = newT;
    }

    // ---- out = max(0, x - T); non-temporal stores (output never re-read,
    //      keeps the exactly-L3-sized input resident in Infinity Cache) ----
#pragma unroll
    for (int j = 0; j < 8; ++j) {
        floatx4 o;
        o.x = fmaxf(0.0f, v[j].x - T);
        o.y = fmaxf(0.0f, v[j].y - T);
        o.z = fmaxf(0.0f, v[j].z - T);
        o.w = fmaxf(0.0f, v[j].w - T);
        __builtin_nontemporal_store(o, &xout[j * 64 + lane]);
    }
}

extern "C" void kernel_launch(void* const* d_in, const int* in_sizes, int n_in,
                              void* d_out, int out_size, void* d_ws, size_t ws_size,
                              hipStream_t stream) {
    const float* x = (const float*)d_in[0];
    float* out = (float*)d_out;
    int n_rows = in_sizes[0] / N_COLS;           // 32768
    int blocks = (n_rows + 3) / 4;               // 4 rows (waves) per 256-thread block
    sparsemax_kernel<<<blocks, 256, 0, stream>>>(x, out, n_rows);
}

// Round 5
// 72.338 us; speedup vs baseline: 1.4958x; 1.0132x over previous
//
#include <hip/hip_runtime.h>

// Sparsegen (sigma=0 => sparsemax) along last dim of a [32768, 2048] f32 tensor.
// One 64-lane wave per row; 32 elements/lane in registers (8 x 4 floats).
//
// Michelot's algorithm in ORIGINAL coordinates: T' = (sum_{x>T} x - 1)/cnt
// from the tight lower bound T0 = m - 1 (tau* >= -1). Monotone from below.
//
// R5: wave reductions via DPP (row_shr 1/2/4/8 + row_bcast15/31, pure VALU,
// ~2-4cy/step) instead of __shfl_xor (ds_swizzle, ~30cy + lgkmcnt waits);
// count via ballot+popcount on the SALU pipe; 4-way parallel FP accumulators
// to shorten the serial add chain; sub+clamp epilogue (outputs are in [0,1]).

#define N_COLS 2048

typedef float floatx4 __attribute__((ext_vector_type(4)));

// dpp_ctrl / row_mask / bound_ctrl must be ICEs -> template parameters.
template <int CTRL, int ROW_MASK, bool BC0>
__device__ __forceinline__ float dpp_f(float old_, float src) {
    int r = __builtin_amdgcn_update_dpp(
        __builtin_bit_cast(int, old_), __builtin_bit_cast(int, src),
        CTRL, ROW_MASK, 0xf, BC0);
    return __builtin_bit_cast(float, r);
}

__device__ __forceinline__ float bcast63(float x) {
    return __builtin_bit_cast(float,
        __builtin_amdgcn_readlane(__builtin_bit_cast(int, x), 63));
}

// Sum across 64 lanes; result broadcast to all lanes.
// bound_ctrl=1: shifted-in lanes read 0 (identity for +).
__device__ __forceinline__ float wave_sum(float x) {
    x += dpp_f<0x111, 0xf, true>(0.0f, x);  // row_shr:1
    x += dpp_f<0x112, 0xf, true>(0.0f, x);  // row_shr:2
    x += dpp_f<0x114, 0xf, true>(0.0f, x);  // row_shr:4
    x += dpp_f<0x118, 0xf, true>(0.0f, x);  // row_shr:8  -> lane15 of each row
    x += dpp_f<0x142, 0xa, true>(0.0f, x);  // row_bcast15 -> rows 1,3
    x += dpp_f<0x143, 0xc, true>(0.0f, x);  // row_bcast31 -> lane63 = total
    return bcast63(x);
}

// Max across 64 lanes; invalid lanes keep old=x (identity for max).
__device__ __forceinline__ float wave_max(float x) {
    x = fmaxf(x, dpp_f<0x111, 0xf, false>(x, x));
    x = fmaxf(x, dpp_f<0x112, 0xf, false>(x, x));
    x = fmaxf(x, dpp_f<0x114, 0xf, false>(x, x));
    x = fmaxf(x, dpp_f<0x118, 0xf, false>(x, x));
    x = fmaxf(x, dpp_f<0x142, 0xa, false>(x, x));
    x = fmaxf(x, dpp_f<0x143, 0xc, false>(x, x));
    return bcast63(x);
}

__global__ __launch_bounds__(256) void sparsemax_kernel(
    const float* __restrict__ x, float* __restrict__ out, int n_rows) {
    const int lane = threadIdx.x & 63;
    const int wave = threadIdx.x >> 6;
    const int row  = blockIdx.x * 4 + wave;
    if (row >= n_rows) return;

    const floatx4* __restrict__ xin =
        reinterpret_cast<const floatx4*>(x + (size_t)row * N_COLS);
    floatx4* __restrict__ xout =
        reinterpret_cast<floatx4*>(out + (size_t)row * N_COLS);

    // Coalesced load: lane-contiguous 16B (wave covers the 8KB row).
    floatx4 v[8];
#pragma unroll
    for (int j = 0; j < 8; ++j) v[j] = xin[j * 64 + lane];

    // ---- row max ----
    float m = -INFINITY;
#pragma unroll
    for (int j = 0; j < 8; ++j)
        m = fmaxf(m, fmaxf(fmaxf(v[j].x, v[j].y), fmaxf(v[j].z, v[j].w)));
    m = wave_max(m);

    // ---- Michelot from the tight bound T0 = m - 1 ----
    float T = m - 1.0f;
    for (int it = 0; it < 32; ++it) {
        float p0 = 0.0f, p1 = 0.0f, p2 = 0.0f, p3 = 0.0f;
        int cnt = 0;  // wave-uniform (ballot popcounts, SALU pipe)
#pragma unroll
        for (int j = 0; j < 8; ++j) {
            bool gx = v[j].x > T, gy = v[j].y > T,
                 gz = v[j].z > T, gw = v[j].w > T;
            p0 += gx ? v[j].x : 0.0f;
            p1 += gy ? v[j].y : 0.0f;
            p2 += gz ? v[j].z : 0.0f;
            p3 += gw ? v[j].w : 0.0f;
            cnt += __popcll(__ballot(gx));
            cnt += __popcll(__ballot(gy));
            cnt += __popcll(__ballot(gz));
            cnt += __popcll(__ballot(gw));
        }
        float ps = wave_sum((p0 + p1) + (p2 + p3));
        // cnt >= 1 always: the row max satisfies m > T for all T <= T* < m.
        float newT = (ps - 1.0f) / (float)cnt;
        if (!(newT > T)) break;  // wave-uniform
        T = newT;
    }

    // ---- out = max(0, x - T) = saturate(x - T) (sparsemax outputs <= 1);
    //      non-temporal stores keep the L3 for the input ----
#pragma unroll
    for (int j = 0; j < 8; ++j) {
        floatx4 o;
        o.x = __saturatef(v[j].x - T);
        o.y = __saturatef(v[j].y - T);
        o.z = __saturatef(v[j].z - T);
        o.w = __saturatef(v[j].w - T);
        __builtin_nontemporal_store(o, &xout[j * 64 + lane]);
    }
}

extern "C" void kernel_launch(void* const* d_in, const int* in_sizes, int n_in,
                              void* d_out, int out_size, void* d_ws, size_t ws_size,
                              hipStream_t stream) {
    const float* x = (const float*)d_in[0];
    float* out = (float*)d_out;
    int n_rows = in_sizes[0] / N_COLS;           // 32768
    int blocks = (n_rows + 3) / 4;               // 4 rows (waves) per 256-thread block
    sparsemax_kernel<<<blocks, 256, 0, stream>>>(x, out, n_rows);
}